// Round 1
// baseline (1551.310 us; speedup 1.0000x reference)
//
#include <hip/hip_runtime.h>

// Problem constants
#define NND 8192   // nodes
#define FD  32     // feature dim
#define ED  32     // embedding dim
#define SUP 4      // relations
#define NB  2      // bases

// rgcn_main tiling: 512 blocks = 32 n-blocks x (4 s x 4 k-splits); 128 thr/block
#define BROWS 256          // output rows per block
#define TK    32           // k per LDS step (32 floats = 128 B/row; swizzle -> 2-way free)
#define CHUNK 2048         // k per block (one relation, quarter of N)
#define NSTEP (CHUNK/TK)   // 64

#define FMA4(acc, sa, g) { acc.x += (sa) * (g).x; acc.y += (sa) * (g).y; \
                           acc.z += (sa) * (g).z; acc.w += (sa) * (g).w; }

// Direct global->LDS 16B staging. LDS dest is wave-uniform base + lane*16 (linear);
// bank-conflict fix is applied by swizzling the GLOBAL source address and applying
// the same XOR on the read side (both-sides-or-neither rule).
#define GLDS16(gsrc, ldst) \
  __builtin_amdgcn_global_load_lds((const __attribute__((address_space(1))) void*)(gsrc), \
                                   (__attribute__((address_space(3))) void*)(ldst), 16, 0, 0)

// --------------------------------------------------------------------------
// Kernel 1: G[s][m][e] = sum_f features[m][f] * Veff[s][f][e], and zero out.
// One thread per (s,m): feature row in registers, per-s Veff (4 KB) in LDS.
// Veff[s][f][e] = sum_b Wc[f&3][b] * W[b][s*8 + f/4][e]  (reshape fold, unchanged).
// --------------------------------------------------------------------------
__global__ __launch_bounds__(256) void prep_g(
        const float* __restrict__ features,
        const float* __restrict__ W,
        const float* __restrict__ Wc,
        float* __restrict__ G,
        float* __restrict__ out) {
    __shared__ __align__(16) float Vlds[FD * ED];   // 4 KB: this block's s only
    const int t   = threadIdx.x;
    const int gid = blockIdx.x * 256 + t;           // 0..32767
    const int s   = gid >> 13;                      // uniform within a block
    const int m   = gid & (NND - 1);

    for (int i = t; i < FD * ED; i += 256) {
        const int e  = i & 31;
        const int f  = i >> 5;
        const int f2 = s * 8 + (f >> 2);
        const int s2 = f & 3;
        float v = 0.f;
        #pragma unroll
        for (int b = 0; b < NB; ++b)
            v += Wc[s2 * NB + b] * W[(b * FD + f2) * ED + e];
        Vlds[i] = v;
    }
    __syncthreads();

    // Zero the output accumulator (65536 float4 over 32768 threads)
    float4* out4 = (float4*)out;
    const float4 z = {0.f, 0.f, 0.f, 0.f};
    out4[gid]         = z;
    out4[gid + 32768] = z;

    // Feature row -> registers
    const float4* feat4 = (const float4*)(features + (size_t)m * FD);
    float4 fr[8];
    #pragma unroll
    for (int i = 0; i < 8; ++i) fr[i] = feat4[i];

    float4 acc[8];
    #pragma unroll
    for (int i = 0; i < 8; ++i) acc[i] = z;

    const float4* V4 = (const float4*)Vlds;         // broadcast reads (free)
    #pragma unroll
    for (int f = 0; f < FD; ++f) {
        const float fv = ((const float*)fr)[f];     // static index (unrolled)
        #pragma unroll
        for (int e4 = 0; e4 < 8; ++e4) {
            const float4 v = V4[f * 8 + e4];
            FMA4(acc[e4], fv, v);
        }
    }
    float4* g4 = (float4*)(G + ((size_t)s * NND + m) * ED);
    #pragma unroll
    for (int e4 = 0; e4 < 8; ++e4) g4[e4] = acc[e4];
}

// --------------------------------------------------------------------------
// Kernel 2: out[n][e] += sum_{m in chunk} A[s][n][m] * G[s][m][e]
// 128 threads (2 waves). Output tile 256 rows x 32 e; 8 rows x 8 e per thread
// (1 B LDS per FMA). A staged via global_load_lds (16B) with XOR-swizzled
// source; 2-deep double buffer: stage(t+1) issued before compute(t), the
// end-of-step __syncthreads (vmcnt(0)) is the only wait.
// --------------------------------------------------------------------------
__global__ __launch_bounds__(128, 1) void rgcn_main(
        const float* __restrict__ A,
        const float* __restrict__ G,
        float* __restrict__ out) {
    __shared__ __align__(16) float Asb[2][BROWS * TK];  // 2 x 32 KB
    __shared__ __align__(16) float Gsb[2][TK * ED];     // 2 x 4 KB   -> 72 KB: 2 blocks/CU

    const int t  = threadIdx.x;
    const int bx = blockIdx.x;           // 512 blocks
    const int nb = bx & 31;              // 32 n-blocks
    const int kb = bx >> 5;              // 16 k-chunks
    const int s       = kb >> 2;         // relation
    const int m_start = (kb & 3) * CHUNK;
    const int n0      = nb * BROWS;

    const float* Ab = A + ((size_t)s * NND + n0) * NND + m_start;   // + row*NND + m_local
    const float* Gb = G + (size_t)s * NND * ED + (size_t)m_start * ED;

    const int w    = t >> 6;             // wave 0..1
    const int lane = t & 63;
    const int lr   = lane >> 3;          // row within 8-row group (stage)
    const int lc   = lane & 7;           // 16B-granule slot (stage)

    // Stage one step's tiles into buf. A: 32 instrs (16/wave), each 1 KB = 8 rows.
    // Slot c4 of row holds global column granule (c4 ^ (rowgroup&7)); rowgroup = inst.
    auto stage = [&](int step, int buf) {
        const int m0 = step * TK;
        #pragma unroll
        for (int i = 0; i < 16; ++i) {
            const int inst = w * 16 + i;
            const int row  = inst * 8 + lr;
            const int c4   = lc ^ (inst & 7);
            GLDS16(Ab + (size_t)row * NND + m0 + (c4 << 2), &Asb[buf][inst * 256]);
        }
        #pragma unroll
        for (int i = 0; i < 2; ++i) {
            const int inst = w * 2 + i;   // G tile: 4 KB contiguous, no swizzle needed
            GLDS16(Gb + (size_t)m0 * ED + inst * 256 + lane * 4, &Gsb[buf][inst * 256]);
        }
    };

    // Compute-side thread mapping: rg = rows rg*8..rg*8+7, eg = e's eg*8..eg*8+7
    const int rg = t >> 2;               // 0..31
    const int eg = t & 3;                // 0..3
    const int sw = rg & 7;               // read-side XOR (matches inst&7 on stage side)

    float4 acc[8][2];
    #pragma unroll
    for (int i = 0; i < 8; ++i) {
        acc[i][0] = float4{0.f, 0.f, 0.f, 0.f};
        acc[i][1] = float4{0.f, 0.f, 0.f, 0.f};
    }

    stage(0, 0);
    __syncthreads();                      // drain stage(0) (vmcnt 0) + sync

    for (int step = 0; step < NSTEP; ++step) {
        const int buf = step & 1;
        if (step + 1 < NSTEP) stage(step + 1, buf ^ 1);   // loads fly during compute

        const float* As = Asb[buf];
        const float* Gs = Gsb[buf];
        #pragma unroll
        for (int k4 = 0; k4 < 8; ++k4) {  // 4 k per micro-step
            float4 a[8];
            #pragma unroll
            for (int i = 0; i < 8; ++i)   // 16 distinct rows/wave, 2-way banks = free
                a[i] = *(const float4*)&As[(rg * 8 + i) * TK + ((k4 ^ sw) << 2)];
            float4 g[4][2];
            #pragma unroll
            for (int kk = 0; kk < 4; ++kk) {
                g[kk][0] = *(const float4*)&Gs[(k4 * 4 + kk) * ED + eg * 8];
                g[kk][1] = *(const float4*)&Gs[(k4 * 4 + kk) * ED + eg * 8 + 4];
            }
            #pragma unroll
            for (int i = 0; i < 8; ++i) {
                #pragma unroll
                for (int h = 0; h < 2; ++h) {
                    FMA4(acc[i][h], a[i].x, g[0][h]);
                    FMA4(acc[i][h], a[i].y, g[1][h]);
                    FMA4(acc[i][h], a[i].z, g[2][h]);
                    FMA4(acc[i][h], a[i].w, g[3][h]);
                }
            }
        }
        // Drains this wave's prefetch (vmcnt 0) and guarantees all waves are done
        // reading buf before next iteration's stage overwrites it.
        __syncthreads();
    }

    // Epilogue: 16 split-K contributions per output element (4 s x 4 chunks)
    #pragma unroll
    for (int i = 0; i < 8; ++i) {
        float* p = out + (size_t)(n0 + rg * 8 + i) * ED + eg * 8;
        #pragma unroll
        for (int h = 0; h < 2; ++h) {
            atomicAdd(p + h * 4 + 0, acc[i][h].x);
            atomicAdd(p + h * 4 + 1, acc[i][h].y);
            atomicAdd(p + h * 4 + 2, acc[i][h].z);
            atomicAdd(p + h * 4 + 3, acc[i][h].w);
        }
    }
}

extern "C" void kernel_launch(void* const* d_in, const int* in_sizes, int n_in,
                              void* d_out, int out_size, void* d_ws, size_t ws_size,
                              hipStream_t stream) {
    const float* features = (const float*)d_in[0];
    const float* A        = (const float*)d_in[1];
    const float* W        = (const float*)d_in[2];
    const float* Wc       = (const float*)d_in[3];
    float* out = (float*)d_out;
    float* G   = (float*)d_ws;   // 4*8192*32 floats = 4 MB

    prep_g<<<128, 256, 0, stream>>>(features, W, Wc, G, out);
    rgcn_main<<<32 * 16, 128, 0, stream>>>(A, G, out);
}